// Round 4
// baseline (97255.200 us; speedup 1.0000x reference)
//
#include <hip/hip_runtime.h>
#include <math.h>

#define NROWS 4096
#define DZ    128
#define DH    512
#define VOC   64
#define DE    128
#define MAXLEN 128
#define PAD_T 0
#define SOS_T 1
#define EOS_T 2

// ---------------- transpose: in [R][C] -> out [C][R] ----------------
__global__ void transpose_k(const float* __restrict__ in, float* __restrict__ out,
                            int R, int C) {
  __shared__ float tile[32][33];
  int cb = blockIdx.x * 32, rb = blockIdx.y * 32;
  int tx = threadIdx.x, ty = threadIdx.y;  // blockDim (32,8)
  #pragma unroll
  for (int i = ty; i < 32; i += 8)
    tile[i][tx] = in[(size_t)(rb + i) * C + (cb + tx)];
  __syncthreads();
  #pragma unroll
  for (int i = ty; i < 32; i += 8)
    out[(size_t)(cb + i) * R + (rb + tx)] = tile[tx][i];
}

// ---------------- repack: in [Rn][K] -> plane P[((k>>2)*Rn + r)*4 + (k&3)] ----
__global__ void repack_k(const float* __restrict__ in, float* __restrict__ out,
                         int Rn, int K) {
  int k = blockIdx.y * 128 + threadIdx.x;
  int r = blockIdx.x;
  out[((size_t)(k >> 2) * Rn + r) * 4 + (k & 3)] = in[(size_t)r * K + k];
}

// ---------------- G0[v] = emb[v] @ W_ih0^T + b_ih0  (uses packed Wi0) --------
__global__ __launch_bounds__(64) void build_g0(
    const float* __restrict__ emb, const float* __restrict__ P,
    const float* __restrict__ bi, float* __restrict__ G0) {
  int lane = threadIdx.x;
  int j = blockIdx.x * 64 + lane;   // grid.x = DH/64
  int v = blockIdx.y;               // grid.y = VOC
  const size_t KDH = (size_t)DE * DH;
  const float4* e4 = (const float4*)(emb + (size_t)v * DE);
  float ar = bi[j], az = bi[DH + j], an = bi[2 * DH + j];
  for (int k4 = 0; k4 < DE / 4; ++k4) {
    size_t off = ((size_t)k4 * DH + j);
    float4 wr = ((const float4*)P)[off];
    float4 wz = ((const float4*)(P + KDH))[off];
    float4 wn = ((const float4*)(P + 2 * KDH))[off];
    float4 x = e4[k4];
    ar = fmaf(x.x, wr.x, ar); ar = fmaf(x.y, wr.y, ar);
    ar = fmaf(x.z, wr.z, ar); ar = fmaf(x.w, wr.w, ar);
    az = fmaf(x.x, wz.x, az); az = fmaf(x.y, wz.y, az);
    az = fmaf(x.z, wz.z, az); az = fmaf(x.w, wz.w, az);
    an = fmaf(x.x, wn.x, an); an = fmaf(x.y, wn.y, an);
    an = fmaf(x.z, wn.z, an); an = fmaf(x.w, wn.w, an);
  }
  G0[(size_t)v * 3 * DH + j] = ar;
  G0[(size_t)v * 3 * DH + DH + j] = az;
  G0[(size_t)v * 3 * DH + 2 * DH + j] = an;
}

// ---------------- fill output: SOS col, PAD body, MAXLEN seq_lens ------------
__global__ void fill_out(int* __restrict__ outi) {
  size_t i = (size_t)blockIdx.x * 256 + threadIdx.x;
  size_t body = (size_t)NROWS * MAXLEN;
  if (i < body)
    outi[i] = ((i & (MAXLEN - 1)) == 0) ? SOS_T : PAD_T;
  else if (i < body + NROWS)
    outi[i] = MAXLEN;
}

// ---------------- init: h0 = Z @ z2h_w^T + b; state + list init --------------
__global__ __launch_bounds__(256) void init_kernel(
    const float* __restrict__ Z, const float* __restrict__ z2hT,
    const float* __restrict__ z2h_b,
    float* __restrict__ h1, float* __restrict__ h2, float* __restrict__ h3,
    int* __restrict__ tok, int* __restrict__ rows0, int* __restrict__ counts) {
  int lane = threadIdx.x & 63;
  int wave = __builtin_amdgcn_readfirstlane((int)(threadIdx.x >> 6));
  int r = blockIdx.x * 4 + wave;          // grid.x = NROWS/4
  int j = blockIdx.y * 64 + lane;         // grid.y = DH/64
  float acc = z2h_b[j];
  const float* zr = Z + (size_t)r * DZ;   // wave-uniform -> s_load
  #pragma unroll 4
  for (int k = 0; k < DZ; ++k)
    acc = fmaf(zr[k], z2hT[(size_t)k * DH + j], acc);
  size_t o = (size_t)r * DH + j;
  h1[o] = acc; h2[o] = acc; h3[o] = acc;
  if (blockIdx.y == 0 && lane == 0) {
    tok[r] = SOS_T;
    rows0[r] = r;
  }
  if (blockIdx.x == 0 && blockIdx.y == 0 && threadIdx.x < MAXLEN + 1)
    counts[threadIdx.x] = (threadIdx.x == 1) ? NROWS : 0;
}

// ---------------- fused GRU cell layer (active-list driven) ----------------
// lane -> gate unit j (64/wave), wave -> 16 active rows; grid (NROWS/64, DH/64).
// Weights packed per gate plane [K/4][DH][4]: one coalesced dwordx4/gate/4k.
// Activations: wave-uniform s_load_dwordx4 via row indirection.
template <bool L0>
__global__ __launch_bounds__(256, 2) void gru_kernel(
    const float* __restrict__ Xin,    // [NROWS][DH]   (L1/L2 only)
    const int* __restrict__ tok,      // [NROWS]       (L0 only)
    const float* __restrict__ G0,     // [VOC][3*DH]   (L0 only)
    const float* __restrict__ Hprev,  // [NROWS][DH]
    const float* __restrict__ WiP,    // packed input weights (L1/L2 only)
    const float* __restrict__ WhP,    // packed hidden weights
    const float* __restrict__ bi, const float* __restrict__ bh,
    const int* __restrict__ cnt, const int* __restrict__ rows,
    float* __restrict__ Hnew) {
  constexpr int R = 16;
  const size_t KDH = (size_t)DH * DH;   // per-gate plane size (K=DH)
  int lane = threadIdx.x & 63;
  int wave = __builtin_amdgcn_readfirstlane((int)(threadIdx.x >> 6));
  int n = *cnt;
  int base = blockIdx.x * (4 * R) + wave * R;  // grid.x = NROWS/64
  if (base >= n) return;                        // wave-uniform exit
  int j  = blockIdx.y * 64 + lane;              // grid.y = DH/64

  int ri[R];
  #pragma unroll
  for (int r = 0; r < R; ++r) {
    int idx = base + r;
    if (idx > n - 1) idx = n - 1;   // clamp: duplicate work, identical stores
    ri[r] = rows[idx];
  }

  float accr[R], accz[R], accin[R], acchn[R];
  float bhr = bh[j], bhz = bh[DH + j], bhn = bh[2 * DH + j];
  if constexpr (L0) {
    #pragma unroll
    for (int r = 0; r < R; ++r) {
      const float* g = G0 + (size_t)tok[ri[r]] * (3 * DH);
      accr[r]  = g[j] + bhr;
      accz[r]  = g[DH + j] + bhz;
      accin[r] = g[2 * DH + j];
      acchn[r] = bhn;
    }
  } else {
    float bir = bi[j], biz = bi[DH + j], bin = bi[2 * DH + j];
    #pragma unroll
    for (int r = 0; r < R; ++r) {
      accr[r] = bir + bhr; accz[r] = biz + bhz; accin[r] = bin; acchn[r] = bhn;
    }
    // phase 1: gi += x @ Wi^T
    const float4* x4[R];
    #pragma unroll
    for (int r = 0; r < R; ++r)
      x4[r] = (const float4*)(Xin + (size_t)ri[r] * DH);
    #pragma unroll 2
    for (int k4 = 0; k4 < DH / 4; ++k4) {
      size_t off = (size_t)k4 * DH + j;
      float4 wr = ((const float4*)WiP)[off];
      float4 wz = ((const float4*)(WiP + KDH))[off];
      float4 wn = ((const float4*)(WiP + 2 * KDH))[off];
      #pragma unroll
      for (int r = 0; r < R; ++r) {
        float4 x = x4[r][k4];   // wave-uniform -> s_load_dwordx4
        accr[r]  = fmaf(x.x, wr.x, accr[r]);  accr[r]  = fmaf(x.y, wr.y, accr[r]);
        accr[r]  = fmaf(x.z, wr.z, accr[r]);  accr[r]  = fmaf(x.w, wr.w, accr[r]);
        accz[r]  = fmaf(x.x, wz.x, accz[r]);  accz[r]  = fmaf(x.y, wz.y, accz[r]);
        accz[r]  = fmaf(x.z, wz.z, accz[r]);  accz[r]  = fmaf(x.w, wz.w, accz[r]);
        accin[r] = fmaf(x.x, wn.x, accin[r]); accin[r] = fmaf(x.y, wn.y, accin[r]);
        accin[r] = fmaf(x.z, wn.z, accin[r]); accin[r] = fmaf(x.w, wn.w, accin[r]);
      }
    }
  }
  // phase 2: gh += h @ Wh^T
  {
    const float4* h4[R];
    #pragma unroll
    for (int r = 0; r < R; ++r)
      h4[r] = (const float4*)(Hprev + (size_t)ri[r] * DH);
    #pragma unroll 2
    for (int k4 = 0; k4 < DH / 4; ++k4) {
      size_t off = (size_t)k4 * DH + j;
      float4 wr = ((const float4*)WhP)[off];
      float4 wz = ((const float4*)(WhP + KDH))[off];
      float4 wn = ((const float4*)(WhP + 2 * KDH))[off];
      #pragma unroll
      for (int r = 0; r < R; ++r) {
        float4 h = h4[r][k4];   // wave-uniform -> s_load_dwordx4
        accr[r]  = fmaf(h.x, wr.x, accr[r]);  accr[r]  = fmaf(h.y, wr.y, accr[r]);
        accr[r]  = fmaf(h.z, wr.z, accr[r]);  accr[r]  = fmaf(h.w, wr.w, accr[r]);
        accz[r]  = fmaf(h.x, wz.x, accz[r]);  accz[r]  = fmaf(h.y, wz.y, accz[r]);
        accz[r]  = fmaf(h.z, wz.z, accz[r]);  accz[r]  = fmaf(h.w, wz.w, accz[r]);
        acchn[r] = fmaf(h.x, wn.x, acchn[r]); acchn[r] = fmaf(h.y, wn.y, acchn[r]);
        acchn[r] = fmaf(h.z, wn.z, acchn[r]); acchn[r] = fmaf(h.w, wn.w, acchn[r]);
      }
    }
  }
  // gates + blend
  #pragma unroll
  for (int r = 0; r < R; ++r) {
    float rg = 1.f / (1.f + expf(-accr[r]));
    float zg = 1.f / (1.f + expf(-accz[r]));
    float nn = tanhf(accin[r] + rg * acchn[r]);
    size_t o = (size_t)ri[r] * DH + j;
    float hp = Hprev[o];
    Hnew[o] = (1.f - zg) * nn + zg * hp;
  }
}

// ---------------- logits + argmax + EOS bookkeeping (list-driven) ------------
// wave -> 4 active rows, lane = vocab id; appends survivors to next list.
__global__ __launch_bounds__(256) void argmax_kernel(
    const float* __restrict__ H3, const float* __restrict__ h2vP,
    const float* __restrict__ h2v_b,
    const int* __restrict__ cnt, const int* __restrict__ rows,
    int* __restrict__ cnt_next, int* __restrict__ rows_next,
    int* __restrict__ tok, int* __restrict__ outi, int t) {
  int lane = threadIdx.x & 63;
  int wave = __builtin_amdgcn_readfirstlane((int)(threadIdx.x >> 6));
  int n = *cnt;
  int base = blockIdx.x * 16 + wave * 4;    // grid.x = NROWS/16
  if (base >= n) return;                     // wave-uniform exit
  int m = n - base; if (m > 4) m = 4;
  int ri[4];
  #pragma unroll
  for (int i = 0; i < 4; ++i) {
    int idx = base + i;
    if (idx > n - 1) idx = n - 1;
    ri[i] = rows[idx];
  }
  float acc[4];
  float b = h2v_b[lane];
  #pragma unroll
  for (int i = 0; i < 4; ++i) acc[i] = b;
  const float4* w4 = (const float4*)h2vP;
  const float4* h4[4];
  #pragma unroll
  for (int i = 0; i < 4; ++i)
    h4[i] = (const float4*)(H3 + (size_t)ri[i] * DH);
  #pragma unroll 2
  for (int k4 = 0; k4 < DH / 4; ++k4) {
    float4 w = w4[(size_t)k4 * VOC + lane];       // coalesced vector
    #pragma unroll
    for (int i = 0; i < 4; ++i) {
      float4 h = h4[i][k4];                        // wave-uniform -> s_load
      acc[i] = fmaf(h.x, w.x, acc[i]); acc[i] = fmaf(h.y, w.y, acc[i]);
      acc[i] = fmaf(h.z, w.z, acc[i]); acc[i] = fmaf(h.w, w.w, acc[i]);
    }
  }
  int win[4];
  #pragma unroll
  for (int i = 0; i < 4; ++i) {
    // argmax across 64 lanes; tie -> lowest index (jnp.argmax = first max)
    float v = acc[i]; int idx = lane;
    #pragma unroll
    for (int off = 32; off >= 1; off >>= 1) {
      float v2 = __shfl_xor(v, off);
      int   i2 = __shfl_xor(idx, off);
      if (v2 > v || (v2 == v && i2 < idx)) { v = v2; idx = i2; }
    }
    win[i] = idx;   // all lanes hold winner
  }
  if (lane == 0) {
    int keep[4]; int nk = 0;
    for (int i = 0; i < m; ++i) {
      int r = ri[i];
      int x_next = win[i];
      outi[(size_t)r * MAXLEN + t] = x_next;     // active => not eos before
      tok[r] = x_next;
      if (x_next == EOS_T)
        outi[(size_t)NROWS * MAXLEN + r] = t + 1;  // seq_lens
      else
        keep[nk++] = r;
    }
    if (nk > 0) {
      int pos = atomicAdd(cnt_next, nk);
      for (int q = 0; q < nk; ++q) rows_next[pos + q] = keep[q];
    }
  }
}

// ---------------- host-side orchestration ----------------
extern "C" void kernel_launch(void* const* d_in, const int* in_sizes, int n_in,
                              void* d_out, int out_size, void* d_ws, size_t ws_size,
                              hipStream_t stream) {
  const float* Z      = (const float*)d_in[0];
  const float* emb    = (const float*)d_in[1];
  const float* z2h_w  = (const float*)d_in[2];
  const float* z2h_b  = (const float*)d_in[3];
  const float* W_ih0  = (const float*)d_in[4];
  const float* W_hh0  = (const float*)d_in[5];
  const float* b_ih0  = (const float*)d_in[6];
  const float* b_hh0  = (const float*)d_in[7];
  const float* W_ih1  = (const float*)d_in[8];
  const float* W_hh1  = (const float*)d_in[9];
  const float* b_ih1  = (const float*)d_in[10];
  const float* b_hh1  = (const float*)d_in[11];
  const float* W_ih2  = (const float*)d_in[12];
  const float* W_hh2  = (const float*)d_in[13];
  const float* b_ih2  = (const float*)d_in[14];
  const float* b_hh2  = (const float*)d_in[15];
  const float* h2v_w  = (const float*)d_in[16];
  const float* h2v_b  = (const float*)d_in[17];
  int* outi = (int*)d_out;

  // workspace layout (all chunks 16B-aligned)
  float* p = (float*)d_ws;
  float* WiP0 = p; p += (size_t)3 * DE * DH;
  float* WhP0 = p; p += (size_t)3 * DH * DH;
  float* WiP1 = p; p += (size_t)3 * DH * DH;
  float* WhP1 = p; p += (size_t)3 * DH * DH;
  float* WiP2 = p; p += (size_t)3 * DH * DH;
  float* WhP2 = p; p += (size_t)3 * DH * DH;
  float* G0   = p; p += (size_t)VOC * 3 * DH;
  float* z2hT = p; p += (size_t)DZ * DH;
  float* h2vP = p; p += (size_t)DH * VOC;
  float* h1a = p; p += (size_t)NROWS * DH;
  float* h1b = p; p += (size_t)NROWS * DH;
  float* h2a = p; p += (size_t)NROWS * DH;
  float* h2b = p; p += (size_t)NROWS * DH;
  float* h3a = p; p += (size_t)NROWS * DH;
  float* h3b = p; p += (size_t)NROWS * DH;
  int* tokb  = (int*)p;
  int* rowsA = tokb + NROWS;
  int* rowsB = rowsA + NROWS;
  int* counts = rowsB + NROWS;   // MAXLEN+1 ints

  // one-time: repack weights per gate plane
  struct WEnt { const float* src; float* dst; int K; };
  WEnt wl[6] = {
    {W_ih0, WiP0, DE}, {W_hh0, WhP0, DH}, {W_ih1, WiP1, DH},
    {W_hh1, WhP1, DH}, {W_ih2, WiP2, DH}, {W_hh2, WhP2, DH}};
  for (int m = 0; m < 6; ++m)
    for (int g = 0; g < 3; ++g)
      repack_k<<<dim3(DH, wl[m].K / 128), 128, 0, stream>>>(
          wl[m].src + (size_t)g * DH * wl[m].K,
          wl[m].dst + (size_t)g * wl[m].K * DH, DH, wl[m].K);
  repack_k<<<dim3(VOC, DH / 128), 128, 0, stream>>>(h2v_w, h2vP, VOC, DH);
  transpose_k<<<dim3(DZ / 32, DH / 32), dim3(32, 8), 0, stream>>>(z2h_w, z2hT, DH, DZ);
  build_g0<<<dim3(DH / 64, VOC), 64, 0, stream>>>(emb, WiP0, b_ih0, G0);

  {
    size_t tot = (size_t)NROWS * MAXLEN + NROWS;
    fill_out<<<(int)((tot + 255) / 256), 256, 0, stream>>>(outi);
  }
  init_kernel<<<dim3(NROWS / 4, DH / 64), 256, 0, stream>>>(
      Z, z2hT, z2h_b, h1a, h2a, h3a, tokb, rowsA, counts);

  float* h1p = h1a; float* h1n = h1b;
  float* h2p = h2a; float* h2n = h2b;
  float* h3p = h3a; float* h3n = h3b;
  int* rcur = rowsA; int* rnxt = rowsB;
  for (int t = 1; t < MAXLEN; ++t) {
    const int* cnt = counts + t;
    int* cnt_next  = counts + t + 1;
    gru_kernel<true><<<dim3(NROWS / 64, DH / 64), 256, 0, stream>>>(
        nullptr, tokb, G0, h1p, nullptr, WhP0, nullptr, b_hh0, cnt, rcur, h1n);
    gru_kernel<false><<<dim3(NROWS / 64, DH / 64), 256, 0, stream>>>(
        h1n, nullptr, nullptr, h2p, WiP1, WhP1, b_ih1, b_hh1, cnt, rcur, h2n);
    gru_kernel<false><<<dim3(NROWS / 64, DH / 64), 256, 0, stream>>>(
        h2n, nullptr, nullptr, h3p, WiP2, WhP2, b_ih2, b_hh2, cnt, rcur, h3n);
    argmax_kernel<<<dim3(NROWS / 16), 256, 0, stream>>>(
        h3n, h2vP, h2v_b, cnt, rcur, cnt_next, rnxt, tokb, outi, t);
    float* tmp;
    tmp = h1p; h1p = h1n; h1n = tmp;
    tmp = h2p; h2p = h2n; h2n = tmp;
    tmp = h3p; h3p = h3n; h3n = tmp;
    int* itmp = rcur; rcur = rnxt; rnxt = itmp;
  }
}

// Round 5
// 78844.360 us; speedup vs baseline: 1.2335x; 1.2335x over previous
//
#include <hip/hip_runtime.h>
#include <math.h>

#define NROWS 4096
#define DZ    128
#define DH    512
#define VOC   64
#define DE    128
#define MAXLEN 128
#define PAD_T 0
#define SOS_T 1
#define EOS_T 2

typedef float v2f __attribute__((ext_vector_type(2)));
#define FMA2(a, b, c) __builtin_elementwise_fma((a), (b), (c))

// ---------------- transpose: in [R][C] -> out [C][R] ----------------
__global__ void transpose_k(const float* __restrict__ in, float* __restrict__ out,
                            int R, int C) {
  __shared__ float tile[32][33];
  int cb = blockIdx.x * 32, rb = blockIdx.y * 32;
  int tx = threadIdx.x, ty = threadIdx.y;  // blockDim (32,8)
  #pragma unroll
  for (int i = ty; i < 32; i += 8)
    tile[i][tx] = in[(size_t)(rb + i) * C + (cb + tx)];
  __syncthreads();
  #pragma unroll
  for (int i = ty; i < 32; i += 8)
    out[(size_t)(cb + i) * R + (rb + tx)] = tile[tx][i];
}

// ---------------- repack: in [Rn][K] -> plane P[((k>>2)*Rn + r)*4 + (k&3)] ----
__global__ void repack_k(const float* __restrict__ in, float* __restrict__ out,
                         int Rn, int K) {
  int k = blockIdx.y * 128 + threadIdx.x;
  int r = blockIdx.x;
  out[((size_t)(k >> 2) * Rn + r) * 4 + (k & 3)] = in[(size_t)r * K + k];
}

// ---------------- G0[v] = emb[v] @ W_ih0^T + b_ih0  (uses packed Wi0) --------
__global__ __launch_bounds__(64) void build_g0(
    const float* __restrict__ emb, const float* __restrict__ P,
    const float* __restrict__ bi, float* __restrict__ G0) {
  int lane = threadIdx.x;
  int j = blockIdx.x * 64 + lane;   // grid.x = DH/64
  int v = blockIdx.y;               // grid.y = VOC
  const size_t KDH = (size_t)DE * DH;
  const float4* e4 = (const float4*)(emb + (size_t)v * DE);
  float ar = bi[j], az = bi[DH + j], an = bi[2 * DH + j];
  for (int k4 = 0; k4 < DE / 4; ++k4) {
    size_t off = ((size_t)k4 * DH + j);
    float4 wr = ((const float4*)P)[off];
    float4 wz = ((const float4*)(P + KDH))[off];
    float4 wn = ((const float4*)(P + 2 * KDH))[off];
    float4 x = e4[k4];
    ar = fmaf(x.x, wr.x, ar); ar = fmaf(x.y, wr.y, ar);
    ar = fmaf(x.z, wr.z, ar); ar = fmaf(x.w, wr.w, ar);
    az = fmaf(x.x, wz.x, az); az = fmaf(x.y, wz.y, az);
    az = fmaf(x.z, wz.z, az); az = fmaf(x.w, wz.w, az);
    an = fmaf(x.x, wn.x, an); an = fmaf(x.y, wn.y, an);
    an = fmaf(x.z, wn.z, an); an = fmaf(x.w, wn.w, an);
  }
  G0[(size_t)v * 3 * DH + j] = ar;
  G0[(size_t)v * 3 * DH + DH + j] = az;
  G0[(size_t)v * 3 * DH + 2 * DH + j] = an;
}

// ---------------- init: h0 = Z @ z2h_w^T + b; state init ----------------
__global__ __launch_bounds__(256) void init_kernel(
    const float* __restrict__ Z, const float* __restrict__ z2hT,
    const float* __restrict__ z2h_b,
    float* __restrict__ h1, float* __restrict__ h2, float* __restrict__ h3,
    int* __restrict__ tok, int* __restrict__ eos, int* __restrict__ outi) {
  int lane = threadIdx.x & 63;
  int wave = __builtin_amdgcn_readfirstlane((int)(threadIdx.x >> 6));
  int r = blockIdx.x * 4 + wave;          // grid.x = NROWS/4
  int j = blockIdx.y * 64 + lane;         // grid.y = DH/64
  float acc = z2h_b[j];
  const float* zr = Z + (size_t)r * DZ;   // wave-uniform -> s_load
  #pragma unroll 4
  for (int k = 0; k < DZ; ++k)
    acc = fmaf(zr[k], z2hT[(size_t)k * DH + j], acc);
  size_t o = (size_t)r * DH + j;
  h1[o] = acc; h2[o] = acc; h3[o] = acc;
  if (blockIdx.y == 0 && lane == 0) {
    tok[r] = SOS_T;
    eos[r] = 0;
    outi[(size_t)r * MAXLEN] = SOS_T;               // X_gen[:,0] = SOS
    outi[(size_t)NROWS * MAXLEN + r] = MAXLEN;      // seq_lens init
  }
}

// ---------------- fused GRU cell layer ----------------
// Round-2 mapping: lane -> gate unit j (64/wave), wave -> 8 rows; grid (128, 8).
// NEW: (a) weight stream staged through LDS ping-pong (4 waves of the wg read
// identical bytes -> 4x less L1 return traffic); (b) float2 accumulators over
// (even-k, odd-k) -> v_pk_fma_f32, halving VALU issue.
template <bool IS_L0>
__global__ __launch_bounds__(256, 4) void gru_kernel(
    const float* __restrict__ Xin,    // [NROWS][DH]   (L1/L2 only)
    const int* __restrict__ tok,      // [NROWS]       (L0 only)
    const float* __restrict__ G0,     // [VOC][3*DH]   (L0 only)
    const float* __restrict__ Hprev,  // [NROWS][DH]
    const float* __restrict__ WiP,    // packed [3][K/4][DH][4] (L1/L2 only)
    const float* __restrict__ WhP,    // packed [3][K/4][DH][4]
    const float* __restrict__ bi, const float* __restrict__ bh,
    float* __restrict__ Hnew) {
  constexpr int R = 8;
  constexpr int KC = 4;                 // k4 per LDS chunk
  constexpr int NC = (DH / 4) / KC;     // 32 chunks per phase
  constexpr int CF4 = KC * 3 * 64;      // 768 float4 per chunk (12 KB)
  __shared__ float4 smem[2 * CF4];      // 24 KB ping-pong

  const int tid  = threadIdx.x;
  const int lane = tid & 63;
  const int wave = __builtin_amdgcn_readfirstlane(tid >> 6);
  const int r0 = blockIdx.x * 32 + wave * 8;   // grid.x = NROWS/32
  const int j  = blockIdx.y * 64 + lane;       // grid.y = DH/64
  const int j0 = blockIdx.y * 64;
  const size_t PLANE4 = (size_t)DH * DH / 4;   // per-gate plane, float4 units

  // staging index decomposition (3 float4 per thread per chunk)
  int fidx[3], fkk[3], fg[3];
  #pragma unroll
  for (int p = 0; p < 3; ++p) {
    int f = p * 256 + tid;        // 0..767
    int seg = f >> 6;             // 12 segments: seg = kk*3 + g
    fidx[p] = f & 63;
    fkk[p] = seg / 3;
    fg[p]  = seg - 3 * (seg / 3);
  }

  v2f aR[R], aZ[R], aIN[R], aHN[R];
  {
    float bhr = bh[j], bhz = bh[DH + j], bhn = bh[2 * DH + j];
    if constexpr (IS_L0) {
      #pragma unroll
      for (int r = 0; r < R; ++r) {
        const float* g = G0 + (size_t)tok[r0 + r] * (3 * DH);
        aR[r]  = {g[j] + bhr, 0.f};
        aZ[r]  = {g[DH + j] + bhz, 0.f};
        aIN[r] = {g[2 * DH + j], 0.f};
        aHN[r] = {bhn, 0.f};
      }
    } else {
      float bir = bi[j], biz = bi[DH + j], bin = bi[2 * DH + j];
      #pragma unroll
      for (int r = 0; r < R; ++r) {
        aR[r]  = {bir + bhr, 0.f};
        aZ[r]  = {biz + bhz, 0.f};
        aIN[r] = {bin, 0.f};
        aHN[r] = {bhn, 0.f};
      }
    }
  }

  float4 st0, st1, st2;

  // ---- phase 1: gi += x @ Wi^T (L1/L2 only) ----
  if constexpr (!IS_L0) {
    const float4* x4[R];
    #pragma unroll
    for (int r = 0; r < R; ++r)
      x4[r] = (const float4*)(Xin + (size_t)(r0 + r) * DH);  // uniform -> s_load
    const float4* W4 = (const float4*)WiP;
    st0 = W4[(size_t)fg[0] * PLANE4 + (size_t)fkk[0] * DH + j0 + fidx[0]];
    st1 = W4[(size_t)fg[1] * PLANE4 + (size_t)fkk[1] * DH + j0 + fidx[1]];
    st2 = W4[(size_t)fg[2] * PLANE4 + (size_t)fkk[2] * DH + j0 + fidx[2]];
    smem[0 * 256 + tid] = st0; smem[1 * 256 + tid] = st1; smem[2 * 256 + tid] = st2;
    __syncthreads();
    for (int c = 0; c < NC; ++c) {
      const float4* S = smem + (c & 1) * CF4;
      if (c + 1 < NC) {
        int kb = (c + 1) * KC;
        st0 = W4[(size_t)fg[0] * PLANE4 + (size_t)(kb + fkk[0]) * DH + j0 + fidx[0]];
        st1 = W4[(size_t)fg[1] * PLANE4 + (size_t)(kb + fkk[1]) * DH + j0 + fidx[1]];
        st2 = W4[(size_t)fg[2] * PLANE4 + (size_t)(kb + fkk[2]) * DH + j0 + fidx[2]];
      }
      #pragma unroll
      for (int kk = 0; kk < KC; ++kk) {
        float4 wr4 = S[(kk * 3 + 0) * 64 + lane];
        float4 wz4 = S[(kk * 3 + 1) * 64 + lane];
        float4 wn4 = S[(kk * 3 + 2) * 64 + lane];
        v2f wr01 = {wr4.x, wr4.y}, wr23 = {wr4.z, wr4.w};
        v2f wz01 = {wz4.x, wz4.y}, wz23 = {wz4.z, wz4.w};
        v2f wn01 = {wn4.x, wn4.y}, wn23 = {wn4.z, wn4.w};
        #pragma unroll
        for (int r = 0; r < R; ++r) {
          float4 x = x4[r][c * KC + kk];   // wave-uniform -> s_load_dwordx4
          v2f x01 = {x.x, x.y}, x23 = {x.z, x.w};
          aR[r]  = FMA2(x01, wr01, aR[r]);  aR[r]  = FMA2(x23, wr23, aR[r]);
          aZ[r]  = FMA2(x01, wz01, aZ[r]);  aZ[r]  = FMA2(x23, wz23, aZ[r]);
          aIN[r] = FMA2(x01, wn01, aIN[r]); aIN[r] = FMA2(x23, wn23, aIN[r]);
        }
      }
      if (c + 1 < NC) {
        float4* D = smem + ((c + 1) & 1) * CF4;
        D[0 * 256 + tid] = st0; D[1 * 256 + tid] = st1; D[2 * 256 + tid] = st2;
      }
      __syncthreads();
    }
  }

  // ---- phase 2: gh += h @ Wh^T ----
  {
    const float4* h4[R];
    #pragma unroll
    for (int r = 0; r < R; ++r)
      h4[r] = (const float4*)(Hprev + (size_t)(r0 + r) * DH);  // uniform -> s_load
    const float4* W4 = (const float4*)WhP;
    st0 = W4[(size_t)fg[0] * PLANE4 + (size_t)fkk[0] * DH + j0 + fidx[0]];
    st1 = W4[(size_t)fg[1] * PLANE4 + (size_t)fkk[1] * DH + j0 + fidx[1]];
    st2 = W4[(size_t)fg[2] * PLANE4 + (size_t)fkk[2] * DH + j0 + fidx[2]];
    smem[0 * 256 + tid] = st0; smem[1 * 256 + tid] = st1; smem[2 * 256 + tid] = st2;
    __syncthreads();
    for (int c = 0; c < NC; ++c) {
      const float4* S = smem + (c & 1) * CF4;
      if (c + 1 < NC) {
        int kb = (c + 1) * KC;
        st0 = W4[(size_t)fg[0] * PLANE4 + (size_t)(kb + fkk[0]) * DH + j0 + fidx[0]];
        st1 = W4[(size_t)fg[1] * PLANE4 + (size_t)(kb + fkk[1]) * DH + j0 + fidx[1]];
        st2 = W4[(size_t)fg[2] * PLANE4 + (size_t)(kb + fkk[2]) * DH + j0 + fidx[2]];
      }
      #pragma unroll
      for (int kk = 0; kk < KC; ++kk) {
        float4 wr4 = S[(kk * 3 + 0) * 64 + lane];
        float4 wz4 = S[(kk * 3 + 1) * 64 + lane];
        float4 wn4 = S[(kk * 3 + 2) * 64 + lane];
        v2f wr01 = {wr4.x, wr4.y}, wr23 = {wr4.z, wr4.w};
        v2f wz01 = {wz4.x, wz4.y}, wz23 = {wz4.z, wz4.w};
        v2f wn01 = {wn4.x, wn4.y}, wn23 = {wn4.z, wn4.w};
        #pragma unroll
        for (int r = 0; r < R; ++r) {
          float4 h = h4[r][c * KC + kk];   // wave-uniform -> s_load_dwordx4
          v2f h01 = {h.x, h.y}, h23 = {h.z, h.w};
          aR[r]  = FMA2(h01, wr01, aR[r]);  aR[r]  = FMA2(h23, wr23, aR[r]);
          aZ[r]  = FMA2(h01, wz01, aZ[r]);  aZ[r]  = FMA2(h23, wz23, aZ[r]);
          aHN[r] = FMA2(h01, wn01, aHN[r]); aHN[r] = FMA2(h23, wn23, aHN[r]);
        }
      }
      if (c + 1 < NC) {
        float4* D = smem + ((c + 1) & 1) * CF4;
        D[0 * 256 + tid] = st0; D[1 * 256 + tid] = st1; D[2 * 256 + tid] = st2;
      }
      __syncthreads();
    }
  }

  // ---- epilogue: gates + blend ----
  #pragma unroll
  for (int r = 0; r < R; ++r) {
    float gr  = aR[r].x + aR[r].y;
    float gz  = aZ[r].x + aZ[r].y;
    float gin = aIN[r].x + aIN[r].y;
    float ghn = aHN[r].x + aHN[r].y;
    float rg = 1.f / (1.f + expf(-gr));
    float zg = 1.f / (1.f + expf(-gz));
    float nn = tanhf(gin + rg * ghn);
    size_t o = (size_t)(r0 + r) * DH + j;
    float hp = Hprev[o];
    Hnew[o] = (1.f - zg) * nn + zg * hp;
  }
}

// ---------------- logits + argmax + EOS bookkeeping ----------------
// wave -> 4 rows, lane = vocab id; h2v packed [k/4][VOC][4]
__global__ __launch_bounds__(256) void argmax_kernel(
    const float* __restrict__ H3, const float* __restrict__ h2vP,
    const float* __restrict__ h2v_b,
    int* __restrict__ tok, int* __restrict__ eos,
    int* __restrict__ outi, int t) {
  int lane = threadIdx.x & 63;
  int wave = __builtin_amdgcn_readfirstlane((int)(threadIdx.x >> 6));
  int r0 = blockIdx.x * 16 + wave * 4;    // grid.x = NROWS/16
  float acc[4];
  float b = h2v_b[lane];
  #pragma unroll
  for (int i = 0; i < 4; ++i) acc[i] = b;
  const float4* w4 = (const float4*)h2vP;
  const float4* h4[4];
  #pragma unroll
  for (int i = 0; i < 4; ++i)
    h4[i] = (const float4*)(H3 + (size_t)(r0 + i) * DH);
  #pragma unroll 2
  for (int k4 = 0; k4 < DH / 4; ++k4) {
    float4 w = w4[(size_t)k4 * VOC + lane];       // coalesced vector
    #pragma unroll
    for (int i = 0; i < 4; ++i) {
      float4 h = h4[i][k4];                        // wave-uniform -> s_load
      acc[i] = fmaf(h.x, w.x, acc[i]); acc[i] = fmaf(h.y, w.y, acc[i]);
      acc[i] = fmaf(h.z, w.z, acc[i]); acc[i] = fmaf(h.w, w.w, acc[i]);
    }
  }
  #pragma unroll
  for (int i = 0; i < 4; ++i) {
    // argmax across 64 lanes; tie -> lowest index (jnp.argmax = first max)
    float v = acc[i]; int idx = lane;
    #pragma unroll
    for (int off = 32; off >= 1; off >>= 1) {
      float v2 = __shfl_xor(v, off);
      int   i2 = __shfl_xor(idx, off);
      if (v2 > v || (v2 == v && i2 < idx)) { v = v2; idx = i2; }
    }
    if (lane == 0) {
      int r = r0 + i;
      int e = eos[r];
      int x_next = idx;
      outi[(size_t)r * MAXLEN + t] = e ? PAD_T : x_next;
      if (!e && x_next == EOS_T) {
        outi[(size_t)NROWS * MAXLEN + r] = t + 1;  // seq_lens
        eos[r] = 1;
      }
      tok[r] = x_next;  // raw x_next feeds back
    }
  }
}

// ---------------- host-side orchestration ----------------
extern "C" void kernel_launch(void* const* d_in, const int* in_sizes, int n_in,
                              void* d_out, int out_size, void* d_ws, size_t ws_size,
                              hipStream_t stream) {
  const float* Z      = (const float*)d_in[0];
  const float* emb    = (const float*)d_in[1];
  const float* z2h_w  = (const float*)d_in[2];
  const float* z2h_b  = (const float*)d_in[3];
  const float* W_ih0  = (const float*)d_in[4];
  const float* W_hh0  = (const float*)d_in[5];
  const float* b_ih0  = (const float*)d_in[6];
  const float* b_hh0  = (const float*)d_in[7];
  const float* W_ih1  = (const float*)d_in[8];
  const float* W_hh1  = (const float*)d_in[9];
  const float* b_ih1  = (const float*)d_in[10];
  const float* b_hh1  = (const float*)d_in[11];
  const float* W_ih2  = (const float*)d_in[12];
  const float* W_hh2  = (const float*)d_in[13];
  const float* b_ih2  = (const float*)d_in[14];
  const float* b_hh2  = (const float*)d_in[15];
  const float* h2v_w  = (const float*)d_in[16];
  const float* h2v_b  = (const float*)d_in[17];
  int* outi = (int*)d_out;

  // workspace layout (all chunks 16B-aligned)
  float* p = (float*)d_ws;
  float* WiP0 = p; p += (size_t)3 * DE * DH;
  float* WhP0 = p; p += (size_t)3 * DH * DH;
  float* WiP1 = p; p += (size_t)3 * DH * DH;
  float* WhP1 = p; p += (size_t)3 * DH * DH;
  float* WiP2 = p; p += (size_t)3 * DH * DH;
  float* WhP2 = p; p += (size_t)3 * DH * DH;
  float* G0   = p; p += (size_t)VOC * 3 * DH;
  float* z2hT = p; p += (size_t)DZ * DH;
  float* h2vP = p; p += (size_t)DH * VOC;
  float* h1a = p; p += (size_t)NROWS * DH;
  float* h1b = p; p += (size_t)NROWS * DH;
  float* h2a = p; p += (size_t)NROWS * DH;
  float* h2b = p; p += (size_t)NROWS * DH;
  float* h3a = p; p += (size_t)NROWS * DH;
  float* h3b = p; p += (size_t)NROWS * DH;
  int* tokb = (int*)p;
  int* eosb = tokb + NROWS;

  // one-time: repack weights per gate plane
  struct WEnt { const float* src; float* dst; int K; };
  WEnt wl[6] = {
    {W_ih0, WiP0, DE}, {W_hh0, WhP0, DH}, {W_ih1, WiP1, DH},
    {W_hh1, WhP1, DH}, {W_ih2, WiP2, DH}, {W_hh2, WhP2, DH}};
  for (int m = 0; m < 6; ++m)
    for (int g = 0; g < 3; ++g)
      repack_k<<<dim3(DH, wl[m].K / 128), 128, 0, stream>>>(
          wl[m].src + (size_t)g * DH * wl[m].K,
          wl[m].dst + (size_t)g * wl[m].K * DH, DH, wl[m].K);
  repack_k<<<dim3(VOC, DH / 128), 128, 0, stream>>>(h2v_w, h2vP, VOC, DH);
  transpose_k<<<dim3(DZ / 32, DH / 32), dim3(32, 8), 0, stream>>>(z2h_w, z2hT, DH, DZ);
  build_g0<<<dim3(DH / 64, VOC), 64, 0, stream>>>(emb, WiP0, b_ih0, G0);

  init_kernel<<<dim3(NROWS / 4, DH / 64), 256, 0, stream>>>(
      Z, z2hT, z2h_b, h1a, h2a, h3a, tokb, eosb, outi);

  float* h1p = h1a; float* h1n = h1b;
  float* h2p = h2a; float* h2n = h2b;
  float* h3p = h3a; float* h3n = h3b;
  for (int t = 1; t < MAXLEN; ++t) {
    gru_kernel<true><<<dim3(NROWS / 32, DH / 64), 256, 0, stream>>>(
        nullptr, tokb, G0, h1p, nullptr, WhP0, nullptr, b_hh0, h1n);
    gru_kernel<false><<<dim3(NROWS / 32, DH / 64), 256, 0, stream>>>(
        h1n, nullptr, nullptr, h2p, WiP1, WhP1, b_ih1, b_hh1, h2n);
    gru_kernel<false><<<dim3(NROWS / 32, DH / 64), 256, 0, stream>>>(
        h2n, nullptr, nullptr, h3p, WiP2, WhP2, b_ih2, b_hh2, h3n);
    argmax_kernel<<<dim3(NROWS / 16), 256, 0, stream>>>(
        h3n, h2vP, h2v_b, tokb, eosb, outi, t);
    float* tmp;
    tmp = h1p; h1p = h1n; h1n = tmp;
    tmp = h2p; h2p = h2n; h2n = tmp;
    tmp = h3p; h3p = h3n; h3n = tmp;
  }
}